// Round 1
// baseline (3720.036 us; speedup 1.0000x reference)
//
#include <hip/hip_runtime.h>

// GCN: 3 layers, dims 64->64->64->32, N=100000 nodes, E=1600000 edges.
// deg[i] = 1 + indegree; dis = rsqrt(deg)
// per layer: h = X@W; agg[i] = sum_{e: dst=i} h[src]*dis[src]*dis[dst] + h[i]*dis[i]^2
//            out = agg + b; relu (layers 1,2 only)

__global__ void k_init_deg(float* deg, int n) {
    int i = blockIdx.x * blockDim.x + threadIdx.x;
    if (i < n) deg[i] = 1.0f;
}

__global__ void k_accum_deg(const int* __restrict__ dst, float* deg, int E) {
    int i = blockIdx.x * blockDim.x + threadIdx.x;
    if (i < E) unsafeAtomicAdd(&deg[dst[i]], 1.0f);
}

__global__ void k_rsqrt(float* d, int n) {
    int i = blockIdx.x * blockDim.x + threadIdx.x;
    if (i < n) d[i] = rsqrtf(d[i]);
}

// H[n x M] = X[n x K] @ W[K x M], W staged in LDS. 256 threads/block.
template <int K, int M>
__global__ void k_gemm(const float* __restrict__ X, const float* __restrict__ W,
                       float* __restrict__ H, int n) {
    constexpr int ROWS = 256 / M;
    __shared__ float Ws[K * M];
    __shared__ float Xs[ROWS * K];
    int tid = threadIdx.x;
    for (int idx = tid; idx < K * M; idx += 256) Ws[idx] = W[idx];
    int row0 = blockIdx.x * ROWS;
    for (int idx = tid; idx < ROWS * K; idx += 256) {
        int r = idx / K, k = idx % K;
        int row = row0 + r;
        Xs[idx] = (row < n) ? X[(size_t)row * K + k] : 0.0f;
    }
    __syncthreads();
    int r = tid / M, c = tid % M;
    int row = row0 + r;
    if (row >= n) return;
    float sum = 0.0f;
#pragma unroll
    for (int k = 0; k < K; ++k) sum += Xs[r * K + k] * Ws[k * M + c];
    H[(size_t)row * M + c] = sum;
}

// agg[i][f] = h[i][f] * dis[i]^2   (self-loop init; also zero-inits agg)
template <int M>
__global__ void k_selfloop(const float* __restrict__ h, const float* __restrict__ dis,
                           float* __restrict__ agg, int n) {
    int i = blockIdx.x * blockDim.x + threadIdx.x;
    if (i >= n * M) return;
    int node = i / M;
    float d = dis[node];
    agg[i] = h[i] * d * d;
}

// one thread per (edge, 4-feature group): float4 gather + 4 atomic adds
template <int M>
__global__ void k_scatter(const float* __restrict__ h, const float* __restrict__ dis,
                          const int* __restrict__ src, const int* __restrict__ dst,
                          float* __restrict__ agg, int E) {
    constexpr int G = M / 4;
    int tid = blockIdx.x * blockDim.x + threadIdx.x;
    int e = tid / G;
    int g = tid % G;
    if (e >= E) return;
    int s = src[e], d = dst[e];
    float w = dis[s] * dis[d];
    float4 hv = ((const float4*)h)[(size_t)s * G + g];
    float* ap = agg + (size_t)d * M + g * 4;
    unsafeAtomicAdd(ap + 0, hv.x * w);
    unsafeAtomicAdd(ap + 1, hv.y * w);
    unsafeAtomicAdd(ap + 2, hv.z * w);
    unsafeAtomicAdd(ap + 3, hv.w * w);
}

// out[i][f] = (agg[i][f] + b[f])   (+ relu)
template <int M, bool RELU>
__global__ void k_finalize(const float* __restrict__ agg, const float* __restrict__ b,
                           float* __restrict__ out, int n) {
    int i = blockIdx.x * blockDim.x + threadIdx.x;
    if (i >= n * M) return;
    float v = agg[i] + b[i % M];
    if (RELU) v = fmaxf(v, 0.0f);
    out[i] = v;
}

static inline int cdiv(int a, int b) { return (a + b - 1) / b; }

extern "C" void kernel_launch(void* const* d_in, const int* in_sizes, int n_in,
                              void* d_out, int out_size, void* d_ws, size_t ws_size,
                              hipStream_t stream) {
    const float* x   = (const float*)d_in[0];
    const int*   ei  = (const int*)d_in[1];
    const float* W1  = (const float*)d_in[2];
    const float* b1  = (const float*)d_in[3];
    const float* W2  = (const float*)d_in[4];
    const float* b2  = (const float*)d_in[5];
    const float* W3  = (const float*)d_in[6];
    const float* b3  = (const float*)d_in[7];
    float* out = (float*)d_out;

    const int N = in_sizes[0] / 64;
    const int E = in_sizes[1] / 2;
    const int* src = ei;
    const int* dst = ei + E;

    // workspace layout (floats), 256B-ish aligned via padded N
    const size_t Np = (size_t)((N + 63) / 64) * 64;
    float* dis  = (float*)d_ws;            // Np
    float* bufH = dis + Np;                // Np*64  (transformed features h)
    float* bufA = bufH + Np * 64;          // Np*64  (aggregation)
    float* bufX = bufA + Np * 64;          // Np*64  (layer input/output)

    const int B = 256;

    // degree + dis
    k_init_deg<<<cdiv(N, B), B, 0, stream>>>(dis, N);
    k_accum_deg<<<cdiv(E, B), B, 0, stream>>>(dst, dis, E);
    k_rsqrt<<<cdiv(N, B), B, 0, stream>>>(dis, N);

    // ---- layer 1: x(64) -> 64, relu ----
    k_gemm<64, 64><<<cdiv(N, 256 / 64), B, 0, stream>>>(x, W1, bufH, N);
    k_selfloop<64><<<cdiv(N * 64, B), B, 0, stream>>>(bufH, dis, bufA, N);
    k_scatter<64><<<cdiv(E * 16, B), B, 0, stream>>>(bufH, dis, src, dst, bufA, E);
    k_finalize<64, true><<<cdiv(N * 64, B), B, 0, stream>>>(bufA, b1, bufX, N);

    // ---- layer 2: 64 -> 64, relu ----
    k_gemm<64, 64><<<cdiv(N, 256 / 64), B, 0, stream>>>(bufX, W2, bufH, N);
    k_selfloop<64><<<cdiv(N * 64, B), B, 0, stream>>>(bufH, dis, bufA, N);
    k_scatter<64><<<cdiv(E * 16, B), B, 0, stream>>>(bufH, dis, src, dst, bufA, E);
    k_finalize<64, true><<<cdiv(N * 64, B), B, 0, stream>>>(bufA, b2, bufX, N);

    // ---- layer 3: 64 -> 32, no relu ----
    k_gemm<64, 32><<<cdiv(N, 256 / 32), B, 0, stream>>>(bufX, W3, bufH, N);
    k_selfloop<32><<<cdiv(N * 32, B), B, 0, stream>>>(bufH, dis, bufA, N);
    k_scatter<32><<<cdiv(E * 8, B), B, 0, stream>>>(bufH, dis, src, dst, bufA, E);
    k_finalize<32, false><<<cdiv(N * 32, B), B, 0, stream>>>(bufA, b3, out, N);
}

// Round 2
// 798.279 us; speedup vs baseline: 4.6601x; 4.6601x over previous
//
#include <hip/hip_runtime.h>

// GCN: 3 layers, dims 64->64->64->32, N=100000 nodes, E=1600000 edges.
// deg[i] = 1 + indegree; dis = rsqrt(deg)
// per layer: h = X@W; out[i] = sum_{e: dst=i} h[src]*dis[src]*dis[dst]
//                              + h[i]*dis[i]^2 + b ; relu (layers 1,2)
//
// Round 2: CSR-by-dst gather-reduce instead of atomic scatter.
// Round 1 evidence: scatter atomics wrote 1.6 GB/dispatch to HBM (uncached
// device-scope RMW), 3x1360us. Gather reads are L2/L3-cacheable.

__global__ void k_zero_int(int* p, int n) {
    int i = blockIdx.x * blockDim.x + threadIdx.x;
    if (i < n) p[i] = 0;
}

__global__ void k_hist(const int* __restrict__ dst, int* __restrict__ cnt, int E) {
    int i = blockIdx.x * blockDim.x + threadIdx.x;
    if (i < E) atomicAdd(&cnt[dst[i]], 1);
}

__global__ void k_dis(const int* __restrict__ cnt, float* __restrict__ dis, int n) {
    int i = blockIdx.x * blockDim.x + threadIdx.x;
    if (i < n) dis[i] = rsqrtf(1.0f + (float)cnt[i]);
}

// single-workgroup exclusive scan of cnt[0..n) -> row_start[0..n], 1024 threads
__global__ void k_scan(const int* __restrict__ cnt, int* __restrict__ row_start, int n) {
    __shared__ int partial[1024];
    int tid = threadIdx.x;
    int chunk = (n + 1023) / 1024;
    int begin = tid * chunk;
    int end = begin + chunk; if (end > n) end = n;
    int s = 0;
    for (int i = begin; i < end; ++i) s += cnt[i];
    partial[tid] = s;
    __syncthreads();
    for (int off = 1; off < 1024; off <<= 1) {
        int t = (tid >= off) ? partial[tid - off] : 0;
        __syncthreads();
        partial[tid] += t;
        __syncthreads();
    }
    int run = partial[tid] - s;  // exclusive base for this chunk
    for (int i = begin; i < end; ++i) { row_start[i] = run; run += cnt[i]; }
    if (tid == 1023) row_start[n] = partial[1023];
}

__global__ void k_fill(const int* __restrict__ src, const int* __restrict__ dst,
                       const float* __restrict__ dis, const int* __restrict__ row_start,
                       int* __restrict__ cursor, int* __restrict__ csr_src,
                       float* __restrict__ csr_w, int E) {
    int e = blockIdx.x * blockDim.x + threadIdx.x;
    if (e >= E) return;
    int d = dst[e], s = src[e];
    int pos = atomicAdd(&cursor[d], 1);
    int idx = row_start[d] + pos;
    csr_src[idx] = s;
    csr_w[idx] = dis[s] * dis[d];
}

// H[n x M] = X[n x K] @ W[K x M], W staged in LDS. 256 threads/block.
template <int K, int M>
__global__ void k_gemm(const float* __restrict__ X, const float* __restrict__ W,
                       float* __restrict__ H, int n) {
    constexpr int ROWS = 256 / M;
    __shared__ float Ws[K * M];
    __shared__ float Xs[ROWS * K];
    int tid = threadIdx.x;
    for (int idx = tid; idx < K * M; idx += 256) Ws[idx] = W[idx];
    int row0 = blockIdx.x * ROWS;
    for (int idx = tid; idx < ROWS * K; idx += 256) {
        int r = idx / K, k = idx % K;
        int row = row0 + r;
        Xs[idx] = (row < n) ? X[(size_t)row * K + k] : 0.0f;
    }
    __syncthreads();
    int r = tid / M, c = tid % M;
    int row = row0 + r;
    if (row >= n) return;
    float sum = 0.0f;
#pragma unroll
    for (int k = 0; k < K; ++k) sum += Xs[r * K + k] * Ws[k * M + c];
    H[(size_t)row * M + c] = sum;
}

// fused: out[i] = sum_in_edges w*h[src] + h[i]*dis[i]^2 + b ; optional relu
// one lane per (node, feature); M lanes per node.
template <int M, bool RELU>
__global__ void k_aggregate(const float* __restrict__ h, const float* __restrict__ dis,
                            const int* __restrict__ row_start,
                            const int* __restrict__ csr_src, const float* __restrict__ csr_w,
                            const float* __restrict__ b,
                            float* __restrict__ out, int n) {
    int tid = blockIdx.x * blockDim.x + threadIdx.x;
    int node = tid / M, lane = tid % M;
    if (node >= n) return;
    float dn = dis[node];
    float acc = h[(size_t)node * M + lane] * dn * dn;
    int e = row_start[node];
    int end = row_start[node + 1];
    // 2-edge unroll for load ILP
    for (; e + 1 < end; e += 2) {
        int s0 = csr_src[e],     s1 = csr_src[e + 1];
        float w0 = csr_w[e],     w1 = csr_w[e + 1];
        float v0 = h[(size_t)s0 * M + lane];
        float v1 = h[(size_t)s1 * M + lane];
        acc += v0 * w0 + v1 * w1;
    }
    if (e < end) {
        int s0 = csr_src[e];
        acc += h[(size_t)s0 * M + lane] * csr_w[e];
    }
    acc += b[lane];
    if (RELU) acc = fmaxf(acc, 0.0f);
    out[(size_t)node * M + lane] = acc;
}

static inline int cdiv(int a, int b) { return (a + b - 1) / b; }

extern "C" void kernel_launch(void* const* d_in, const int* in_sizes, int n_in,
                              void* d_out, int out_size, void* d_ws, size_t ws_size,
                              hipStream_t stream) {
    const float* x   = (const float*)d_in[0];
    const int*   ei  = (const int*)d_in[1];
    const float* W1  = (const float*)d_in[2];
    const float* b1  = (const float*)d_in[3];
    const float* W2  = (const float*)d_in[4];
    const float* b2  = (const float*)d_in[5];
    const float* W3  = (const float*)d_in[6];
    const float* b3  = (const float*)d_in[7];
    float* out = (float*)d_out;

    const int N = in_sizes[0] / 64;
    const int E = in_sizes[1] / 2;
    const int* src = ei;
    const int* dst = ei + E;

    // workspace layout
    const size_t Np = (size_t)((N + 63) / 64) * 64;
    char* p = (char*)d_ws;
    int*   deg_i     = (int*)p;            p += Np * sizeof(int);
    int*   cursor    = (int*)p;            p += Np * sizeof(int);
    int*   row_start = (int*)p;            p += (Np + 64) * sizeof(int);
    float* dis       = (float*)p;          p += Np * sizeof(float);
    int*   csr_src   = (int*)p;            p += (size_t)E * sizeof(int);
    float* csr_w     = (float*)p;          p += (size_t)E * sizeof(float);
    float* bufH      = (float*)p;          p += Np * 64 * sizeof(float);
    float* bufX      = (float*)p;          p += Np * 64 * sizeof(float);

    const int B = 256;

    // ---- CSR build (once per call) ----
    k_zero_int<<<cdiv(N, B), B, 0, stream>>>(deg_i, N);
    k_zero_int<<<cdiv(N, B), B, 0, stream>>>(cursor, N);
    k_hist<<<cdiv(E, B), B, 0, stream>>>(dst, deg_i, E);
    k_dis<<<cdiv(N, B), B, 0, stream>>>(deg_i, dis, N);
    k_scan<<<1, 1024, 0, stream>>>(deg_i, row_start, N);
    k_fill<<<cdiv(E, B), B, 0, stream>>>(src, dst, dis, row_start, cursor,
                                         csr_src, csr_w, E);

    // ---- layer 1: x(64) -> 64, relu ----
    k_gemm<64, 64><<<cdiv(N, 4), B, 0, stream>>>(x, W1, bufH, N);
    k_aggregate<64, true><<<cdiv(N * 64, B), B, 0, stream>>>(
        bufH, dis, row_start, csr_src, csr_w, b1, bufX, N);

    // ---- layer 2: 64 -> 64, relu ----
    k_gemm<64, 64><<<cdiv(N, 4), B, 0, stream>>>(bufX, W2, bufH, N);
    k_aggregate<64, true><<<cdiv(N * 64, B), B, 0, stream>>>(
        bufH, dis, row_start, csr_src, csr_w, b2, bufX, N);

    // ---- layer 3: 64 -> 32, no relu ----
    k_gemm<64, 32><<<cdiv(N, 8), B, 0, stream>>>(bufX, W3, bufH, N);
    k_aggregate<32, false><<<cdiv(N * 32, B), B, 0, stream>>>(
        bufH, dis, row_start, csr_src, csr_w, b3, out, N);
}

// Round 3
// 472.590 us; speedup vs baseline: 7.8716x; 1.6892x over previous
//
#include <hip/hip_runtime.h>

// GCN: 3 layers, dims 64->64->64->32, N=100000 nodes, E=1600000 edges.
// Round 3: hierarchical scan (was 163us single-WG serial scan = 20% of total),
// wave-per-node float4 aggregate w/ int2-packed edges, 4-output/thread GEMM.

static inline int cdiv(int a, int b) { return (a + b - 1) / b; }

__global__ void k_zero_int(int* p, int n) {
    int i = blockIdx.x * blockDim.x + threadIdx.x;
    if (i < n) p[i] = 0;
}

__global__ void k_hist(const int* __restrict__ dst, int* __restrict__ cnt, int E) {
    int i = blockIdx.x * blockDim.x + threadIdx.x;
    if (i < E) atomicAdd(&cnt[dst[i]], 1);
}

__global__ void k_dis(const int* __restrict__ cnt, float* __restrict__ dis, int n) {
    int i = blockIdx.x * blockDim.x + threadIdx.x;
    if (i < n) dis[i] = rsqrtf(1.0f + (float)cnt[i]);
}

// ---- hierarchical exclusive scan: cnt[0..n) -> row_start[0..n] ----
// 1024 elems per block (256 thr x 4)
#define SCAN_T 256
#define SCAN_V 4
#define SCAN_CHUNK 1024

__global__ void k_scan_partial(const int* __restrict__ cnt, int* __restrict__ bsum, int n) {
    __shared__ int red[SCAN_T];
    int t = threadIdx.x, b = blockIdx.x;
    int base = b * SCAN_CHUNK + t * SCAN_V;
    int s = 0;
#pragma unroll
    for (int j = 0; j < SCAN_V; ++j) { int i = base + j; if (i < n) s += cnt[i]; }
    red[t] = s;
    __syncthreads();
    for (int off = SCAN_T / 2; off > 0; off >>= 1) {
        if (t < off) red[t] += red[t + off];
        __syncthreads();
    }
    if (t == 0) bsum[b] = red[0];
}

// single block, exclusive scan of bsum[0..nb), nb <= 1024
__global__ void k_scan_bsum(int* bsum, int nb) {
    __shared__ int sh[1024];
    int t = threadIdx.x;
    int v = (t < nb) ? bsum[t] : 0;
    sh[t] = v;
    __syncthreads();
    for (int off = 1; off < 1024; off <<= 1) {
        int u = (t >= off) ? sh[t - off] : 0;
        __syncthreads();
        sh[t] += u;
        __syncthreads();
    }
    if (t < nb) bsum[t] = sh[t] - v;  // exclusive
}

__global__ void k_scan_final(const int* __restrict__ cnt, const int* __restrict__ bsum,
                             int* __restrict__ row_start, int n) {
    __shared__ int sh[SCAN_T];
    int t = threadIdx.x, b = blockIdx.x;
    int base = b * SCAN_CHUNK + t * SCAN_V;
    int v[SCAN_V];
    int s = 0;
#pragma unroll
    for (int j = 0; j < SCAN_V; ++j) {
        int i = base + j;
        v[j] = (i < n) ? cnt[i] : 0;
        s += v[j];
    }
    sh[t] = s;
    __syncthreads();
    for (int off = 1; off < SCAN_T; off <<= 1) {
        int u = (t >= off) ? sh[t - off] : 0;
        __syncthreads();
        sh[t] += u;
        __syncthreads();
    }
    int run = sh[t] - s + bsum[b];  // exclusive prefix for this thread's chunk
#pragma unroll
    for (int j = 0; j < SCAN_V; ++j) {
        int i = base + j;
        if (i < n) {
            row_start[i] = run;
            run += v[j];
            if (i == n - 1) row_start[n] = run;
        }
    }
}

// fill CSR: pack (src, weight) as int2 for single dwordx2 load in aggregate
__global__ void k_fill(const int* __restrict__ src, const int* __restrict__ dst,
                       const float* __restrict__ dis, const int* __restrict__ row_start,
                       int* __restrict__ cursor, int2* __restrict__ csr, int E) {
    int e = blockIdx.x * blockDim.x + threadIdx.x;
    if (e >= E) return;
    int d = dst[e], s = src[e];
    int pos = atomicAdd(&cursor[d], 1);
    float w = dis[s] * dis[d];
    csr[row_start[d] + pos] = make_int2(s, __float_as_int(w));
}

// H[n x M] = X[n x K] @ W[K x M]; each thread computes 4 consecutive outputs.
template <int K, int M>
__global__ void k_gemm(const float* __restrict__ X, const float* __restrict__ W,
                       float* __restrict__ H, int n) {
    constexpr int C4 = M / 4;           // float4 col groups
    constexpr int ROWS = 256 / C4;      // rows per block (16 for M=64, 32 for M=32)
    __shared__ float Ws[K * M];
    __shared__ float Xs[ROWS * K];
    int tid = threadIdx.x;
    for (int idx = tid; idx < K * M / 4; idx += 256)
        ((float4*)Ws)[idx] = ((const float4*)W)[idx];
    int row0 = blockIdx.x * ROWS;
    for (int idx = tid; idx < ROWS * K / 4; idx += 256) {
        int r = idx / (K / 4);
        int row = row0 + r;
        ((float4*)Xs)[idx] = (row < n) ? ((const float4*)X)[(size_t)row0 * (K / 4) + idx]
                                       : make_float4(0.f, 0.f, 0.f, 0.f);
    }
    __syncthreads();
    int r = tid / C4, c4 = tid % C4;
    int row = row0 + r;
    if (row >= n) return;
    float4 acc = make_float4(0.f, 0.f, 0.f, 0.f);
#pragma unroll
    for (int k = 0; k < K; ++k) {
        float xv = Xs[r * K + k];
        float4 wv = ((const float4*)Ws)[k * C4 + c4];
        acc.x = fmaf(xv, wv.x, acc.x);
        acc.y = fmaf(xv, wv.y, acc.y);
        acc.z = fmaf(xv, wv.z, acc.z);
        acc.w = fmaf(xv, wv.w, acc.w);
    }
    ((float4*)H)[(size_t)row * C4 + c4] = acc;
}

// fused aggregate: one WAVE per node. G=M/4 float4 feature groups, S=64/G edge
// slots processed concurrently; __shfl_xor reduction across slots at the end.
template <int M, bool RELU>
__global__ void k_aggregate(const float* __restrict__ h, const float* __restrict__ dis,
                            const int* __restrict__ row_start, const int2* __restrict__ csr,
                            const float* __restrict__ b, float* __restrict__ out, int n) {
    constexpr int G = M / 4;   // float4 groups per node row
    constexpr int S = 64 / G;  // edge slots per wave
    int gtid = blockIdx.x * blockDim.x + threadIdx.x;
    int node = gtid >> 6;
    if (node >= n) return;
    int lane = threadIdx.x & 63;
    int fg = lane % G;
    int slot = lane / G;
    int e1 = row_start[node + 1];
    const float4* h4 = (const float4*)h;
    float4 acc = make_float4(0.f, 0.f, 0.f, 0.f);
    for (int e = row_start[node] + slot; e < e1; e += S) {
        int2 pr = csr[e];
        float w = __int_as_float(pr.y);
        float4 v = h4[(size_t)pr.x * G + fg];
        acc.x = fmaf(v.x, w, acc.x);
        acc.y = fmaf(v.y, w, acc.y);
        acc.z = fmaf(v.z, w, acc.z);
        acc.w = fmaf(v.w, w, acc.w);
    }
#pragma unroll
    for (int off = G; off < 64; off <<= 1) {
        acc.x += __shfl_xor(acc.x, off, 64);
        acc.y += __shfl_xor(acc.y, off, 64);
        acc.z += __shfl_xor(acc.z, off, 64);
        acc.w += __shfl_xor(acc.w, off, 64);
    }
    if (slot == 0) {
        float dn = dis[node];
        float s2 = dn * dn;
        float4 hv = h4[(size_t)node * G + fg];
        float4 bb = ((const float4*)b)[fg];
        float4 r;
        r.x = acc.x + hv.x * s2 + bb.x;
        r.y = acc.y + hv.y * s2 + bb.y;
        r.z = acc.z + hv.z * s2 + bb.z;
        r.w = acc.w + hv.w * s2 + bb.w;
        if (RELU) {
            r.x = fmaxf(r.x, 0.f);
            r.y = fmaxf(r.y, 0.f);
            r.z = fmaxf(r.z, 0.f);
            r.w = fmaxf(r.w, 0.f);
        }
        ((float4*)out)[(size_t)node * G + fg] = r;
    }
}

extern "C" void kernel_launch(void* const* d_in, const int* in_sizes, int n_in,
                              void* d_out, int out_size, void* d_ws, size_t ws_size,
                              hipStream_t stream) {
    const float* x   = (const float*)d_in[0];
    const int*   ei  = (const int*)d_in[1];
    const float* W1  = (const float*)d_in[2];
    const float* b1  = (const float*)d_in[3];
    const float* W2  = (const float*)d_in[4];
    const float* b2  = (const float*)d_in[5];
    const float* W3  = (const float*)d_in[6];
    const float* b3  = (const float*)d_in[7];
    float* out = (float*)d_out;

    const int N = in_sizes[0] / 64;
    const int E = in_sizes[1] / 2;
    const int* src = ei;
    const int* dst = ei + E;

    // workspace layout
    const size_t Np = (size_t)((N + 63) / 64) * 64;
    char* p = (char*)d_ws;
    int*   deg_i     = (int*)p;   p += Np * sizeof(int);       // [Np]
    int*   cursor    = (int*)p;   p += Np * sizeof(int);       // [Np] (adjacent to deg_i!)
    int*   row_start = (int*)p;   p += (Np + 64) * sizeof(int);
    int*   bsum      = (int*)p;   p += 1024 * sizeof(int);
    float* dis       = (float*)p; p += Np * sizeof(float);
    int2*  csr       = (int2*)p;  p += (size_t)E * sizeof(int2);
    float* bufH      = (float*)p; p += Np * 64 * sizeof(float);
    float* bufX      = (float*)p; p += Np * 64 * sizeof(float);
    (void)ws_size;

    const int B = 256;
    const int nb = cdiv(N, SCAN_CHUNK);  // 98 for N=100000

    // ---- CSR build ----
    k_zero_int<<<cdiv(2 * (int)Np, B), B, 0, stream>>>(deg_i, 2 * (int)Np);  // deg + cursor
    k_hist<<<cdiv(E, B), B, 0, stream>>>(dst, deg_i, E);
    k_dis<<<cdiv(N, B), B, 0, stream>>>(deg_i, dis, N);
    k_scan_partial<<<nb, SCAN_T, 0, stream>>>(deg_i, bsum, N);
    k_scan_bsum<<<1, 1024, 0, stream>>>(bsum, nb);
    k_scan_final<<<nb, SCAN_T, 0, stream>>>(deg_i, bsum, row_start, N);
    k_fill<<<cdiv(E, B), B, 0, stream>>>(src, dst, dis, row_start, cursor, csr, E);

    // ---- layer 1: x(64) -> 64, relu ----
    k_gemm<64, 64><<<cdiv(N, 16), B, 0, stream>>>(x, W1, bufH, N);
    k_aggregate<64, true><<<cdiv(N * 64, B), B, 0, stream>>>(
        bufH, dis, row_start, csr, b1, bufX, N);

    // ---- layer 2: 64 -> 64, relu ----
    k_gemm<64, 64><<<cdiv(N, 16), B, 0, stream>>>(bufX, W2, bufH, N);
    k_aggregate<64, true><<<cdiv(N * 64, B), B, 0, stream>>>(
        bufH, dis, row_start, csr, b2, bufX, N);

    // ---- layer 3: 64 -> 32, no relu ----
    k_gemm<64, 32><<<cdiv(N, 32), B, 0, stream>>>(bufX, W3, bufH, N);
    k_aggregate<32, false><<<cdiv(N * 64, B), B, 0, stream>>>(
        bufH, dis, row_start, csr, b3, out, N);
}

// Round 4
// 415.871 us; speedup vs baseline: 8.9452x; 1.1364x over previous
//
#include <hip/hip_runtime.h>

// GCN: 3 layers, dims 64->64->64->32, N=100000 nodes, E=1600000 edges.
// Round 4: rank-trick CSR fill (hist's atomicAdd return value IS the rank ->
// fill needs no atomics), 8-col/thread GEMM w/ padded Xs, 2x-unrolled gather.
// Round 3 evidence: k_fill 88us with 102MB WRITE_SIZE (64B-line amplification
// of random 8B scatters) + 1.6M cursor atomics.

static inline int cdiv(int a, int b) { return (a + b - 1) / b; }

__global__ void k_zero_int(int* p, int n) {
    int i = blockIdx.x * blockDim.x + threadIdx.x;
    if (i < n) p[i] = 0;
}

// histogram of dst; also records each edge's within-row arrival rank
__global__ void k_hist(const int* __restrict__ dst, int* __restrict__ cnt,
                       int* __restrict__ rank, int E) {
    int i = blockIdx.x * blockDim.x + threadIdx.x;
    if (i < E) rank[i] = atomicAdd(&cnt[dst[i]], 1);
}

__global__ void k_dis(const int* __restrict__ cnt, float* __restrict__ dis, int n) {
    int i = blockIdx.x * blockDim.x + threadIdx.x;
    if (i < n) dis[i] = rsqrtf(1.0f + (float)cnt[i]);
}

// ---- hierarchical exclusive scan: cnt[0..n) -> row_start[0..n] ----
#define SCAN_T 256
#define SCAN_V 4
#define SCAN_CHUNK 1024

__global__ void k_scan_partial(const int* __restrict__ cnt, int* __restrict__ bsum, int n) {
    __shared__ int red[SCAN_T];
    int t = threadIdx.x, b = blockIdx.x;
    int base = b * SCAN_CHUNK + t * SCAN_V;
    int s = 0;
#pragma unroll
    for (int j = 0; j < SCAN_V; ++j) { int i = base + j; if (i < n) s += cnt[i]; }
    red[t] = s;
    __syncthreads();
    for (int off = SCAN_T / 2; off > 0; off >>= 1) {
        if (t < off) red[t] += red[t + off];
        __syncthreads();
    }
    if (t == 0) bsum[b] = red[0];
}

__global__ void k_scan_bsum(int* bsum, int nb) {
    __shared__ int sh[1024];
    int t = threadIdx.x;
    int v = (t < nb) ? bsum[t] : 0;
    sh[t] = v;
    __syncthreads();
    for (int off = 1; off < 1024; off <<= 1) {
        int u = (t >= off) ? sh[t - off] : 0;
        __syncthreads();
        sh[t] += u;
        __syncthreads();
    }
    if (t < nb) bsum[t] = sh[t] - v;  // exclusive
}

__global__ void k_scan_final(const int* __restrict__ cnt, const int* __restrict__ bsum,
                             int* __restrict__ row_start, int n) {
    __shared__ int sh[SCAN_T];
    int t = threadIdx.x, b = blockIdx.x;
    int base = b * SCAN_CHUNK + t * SCAN_V;
    int v[SCAN_V];
    int s = 0;
#pragma unroll
    for (int j = 0; j < SCAN_V; ++j) {
        int i = base + j;
        v[j] = (i < n) ? cnt[i] : 0;
        s += v[j];
    }
    sh[t] = s;
    __syncthreads();
    for (int off = 1; off < SCAN_T; off <<= 1) {
        int u = (t >= off) ? sh[t - off] : 0;
        __syncthreads();
        sh[t] += u;
        __syncthreads();
    }
    int run = sh[t] - s + bsum[b];
#pragma unroll
    for (int j = 0; j < SCAN_V; ++j) {
        int i = base + j;
        if (i < n) {
            row_start[i] = run;
            run += v[j];
            if (i == n - 1) row_start[n] = run;
        }
    }
}

// atomic-free CSR fill using precomputed ranks
__global__ void k_fill(const int* __restrict__ src, const int* __restrict__ dst,
                       const int* __restrict__ rank, const float* __restrict__ dis,
                       const int* __restrict__ row_start, int2* __restrict__ csr, int E) {
    int e = blockIdx.x * blockDim.x + threadIdx.x;
    if (e >= E) return;
    int d = dst[e], s = src[e];
    float w = dis[s] * dis[d];
    csr[row_start[d] + rank[e]] = make_int2(s, __float_as_int(w));
}

// H[n x M] = X[n x K] @ W[K x M]; 8 outputs/thread, Xs padded +1 vs bank conflicts.
template <int K, int M>
__global__ void k_gemm(const float* __restrict__ X, const float* __restrict__ W,
                       float* __restrict__ H, int n) {
    constexpr int CPT = 8;            // cols per thread
    constexpr int TPR = M / CPT;      // threads per row
    constexpr int ROWS = 256 / TPR;   // rows per block
    constexpr int KP = K + 1;         // padded lead dim
    __shared__ float Ws[K * M];
    __shared__ float Xs[ROWS * KP];
    int tid = threadIdx.x;
    for (int idx = tid; idx < K * M / 4; idx += 256)
        ((float4*)Ws)[idx] = ((const float4*)W)[idx];
    int row0 = blockIdx.x * ROWS;
    for (int idx = tid; idx < ROWS * (K / 4); idx += 256) {
        int r = idx / (K / 4), kq = idx % (K / 4);
        int row = row0 + r;
        float4 v = (row < n) ? ((const float4*)X)[(size_t)row * (K / 4) + kq]
                             : make_float4(0.f, 0.f, 0.f, 0.f);
        Xs[r * KP + kq * 4 + 0] = v.x;
        Xs[r * KP + kq * 4 + 1] = v.y;
        Xs[r * KP + kq * 4 + 2] = v.z;
        Xs[r * KP + kq * 4 + 3] = v.w;
    }
    __syncthreads();
    int r = tid / TPR, c0 = (tid % TPR) * CPT;
    int row = row0 + r;
    if (row >= n) return;
    float4 a0 = make_float4(0.f, 0.f, 0.f, 0.f);
    float4 a1 = make_float4(0.f, 0.f, 0.f, 0.f);
#pragma unroll
    for (int k = 0; k < K; ++k) {
        float xv = Xs[r * KP + k];
        float4 w0 = ((const float4*)Ws)[(k * M + c0) / 4];
        float4 w1 = ((const float4*)Ws)[(k * M + c0) / 4 + 1];
        a0.x = fmaf(xv, w0.x, a0.x);
        a0.y = fmaf(xv, w0.y, a0.y);
        a0.z = fmaf(xv, w0.z, a0.z);
        a0.w = fmaf(xv, w0.w, a0.w);
        a1.x = fmaf(xv, w1.x, a1.x);
        a1.y = fmaf(xv, w1.y, a1.y);
        a1.z = fmaf(xv, w1.z, a1.z);
        a1.w = fmaf(xv, w1.w, a1.w);
    }
    ((float4*)H)[(size_t)row * (M / 4) + c0 / 4] = a0;
    ((float4*)H)[(size_t)row * (M / 4) + c0 / 4 + 1] = a1;
}

// fused aggregate: one WAVE per node; 2-edge unroll per slot for MLP.
template <int M, bool RELU>
__global__ void k_aggregate(const float* __restrict__ h, const float* __restrict__ dis,
                            const int* __restrict__ row_start, const int2* __restrict__ csr,
                            const float* __restrict__ b, float* __restrict__ out, int n) {
    constexpr int G = M / 4;   // float4 groups per node row
    constexpr int S = 64 / G;  // edge slots per wave
    int gtid = blockIdx.x * blockDim.x + threadIdx.x;
    int node = gtid >> 6;
    if (node >= n) return;
    int lane = threadIdx.x & 63;
    int fg = lane % G;
    int slot = lane / G;
    int e1 = row_start[node + 1];
    const float4* h4 = (const float4*)h;
    float4 acc = make_float4(0.f, 0.f, 0.f, 0.f);
    int e = row_start[node] + slot;
    for (; e + S < e1; e += 2 * S) {
        int2 p0 = csr[e];
        int2 p1 = csr[e + S];
        float4 v0 = h4[(size_t)p0.x * G + fg];
        float4 v1 = h4[(size_t)p1.x * G + fg];
        float w0 = __int_as_float(p0.y);
        float w1 = __int_as_float(p1.y);
        acc.x = fmaf(v0.x, w0, acc.x);
        acc.y = fmaf(v0.y, w0, acc.y);
        acc.z = fmaf(v0.z, w0, acc.z);
        acc.w = fmaf(v0.w, w0, acc.w);
        acc.x = fmaf(v1.x, w1, acc.x);
        acc.y = fmaf(v1.y, w1, acc.y);
        acc.z = fmaf(v1.z, w1, acc.z);
        acc.w = fmaf(v1.w, w1, acc.w);
    }
    if (e < e1) {
        int2 p0 = csr[e];
        float w0 = __int_as_float(p0.y);
        float4 v0 = h4[(size_t)p0.x * G + fg];
        acc.x = fmaf(v0.x, w0, acc.x);
        acc.y = fmaf(v0.y, w0, acc.y);
        acc.z = fmaf(v0.z, w0, acc.z);
        acc.w = fmaf(v0.w, w0, acc.w);
    }
#pragma unroll
    for (int off = G; off < 64; off <<= 1) {
        acc.x += __shfl_xor(acc.x, off, 64);
        acc.y += __shfl_xor(acc.y, off, 64);
        acc.z += __shfl_xor(acc.z, off, 64);
        acc.w += __shfl_xor(acc.w, off, 64);
    }
    if (slot == 0) {
        float dn = dis[node];
        float s2 = dn * dn;
        float4 hv = h4[(size_t)node * G + fg];
        float4 bb = ((const float4*)b)[fg];
        float4 r;
        r.x = acc.x + hv.x * s2 + bb.x;
        r.y = acc.y + hv.y * s2 + bb.y;
        r.z = acc.z + hv.z * s2 + bb.z;
        r.w = acc.w + hv.w * s2 + bb.w;
        if (RELU) {
            r.x = fmaxf(r.x, 0.f);
            r.y = fmaxf(r.y, 0.f);
            r.z = fmaxf(r.z, 0.f);
            r.w = fmaxf(r.w, 0.f);
        }
        ((float4*)out)[(size_t)node * G + fg] = r;
    }
}

extern "C" void kernel_launch(void* const* d_in, const int* in_sizes, int n_in,
                              void* d_out, int out_size, void* d_ws, size_t ws_size,
                              hipStream_t stream) {
    const float* x   = (const float*)d_in[0];
    const int*   ei  = (const int*)d_in[1];
    const float* W1  = (const float*)d_in[2];
    const float* b1  = (const float*)d_in[3];
    const float* W2  = (const float*)d_in[4];
    const float* b2  = (const float*)d_in[5];
    const float* W3  = (const float*)d_in[6];
    const float* b3  = (const float*)d_in[7];
    float* out = (float*)d_out;

    const int N = in_sizes[0] / 64;
    const int E = in_sizes[1] / 2;
    const int* src = ei;
    const int* dst = ei + E;

    // workspace layout
    const size_t Np = (size_t)((N + 63) / 64) * 64;
    char* p = (char*)d_ws;
    int*   deg_i     = (int*)p;   p += Np * sizeof(int);
    int*   row_start = (int*)p;   p += (Np + 64) * sizeof(int);
    int*   bsum      = (int*)p;   p += 1024 * sizeof(int);
    float* dis       = (float*)p; p += Np * sizeof(float);
    int*   rank      = (int*)p;   p += (size_t)E * sizeof(int);
    int2*  csr       = (int2*)p;  p += (size_t)E * sizeof(int2);
    float* bufH      = (float*)p; p += Np * 64 * sizeof(float);
    float* bufX      = (float*)p; p += Np * 64 * sizeof(float);
    (void)ws_size;

    const int B = 256;
    const int nb = cdiv(N, SCAN_CHUNK);

    // ---- CSR build ----
    k_zero_int<<<cdiv((int)Np, B), B, 0, stream>>>(deg_i, (int)Np);
    k_hist<<<cdiv(E, B), B, 0, stream>>>(dst, deg_i, rank, E);
    k_dis<<<cdiv(N, B), B, 0, stream>>>(deg_i, dis, N);
    k_scan_partial<<<nb, SCAN_T, 0, stream>>>(deg_i, bsum, N);
    k_scan_bsum<<<1, 1024, 0, stream>>>(bsum, nb);
    k_scan_final<<<nb, SCAN_T, 0, stream>>>(deg_i, bsum, row_start, N);
    k_fill<<<cdiv(E, B), B, 0, stream>>>(src, dst, rank, dis, row_start, csr, E);

    // ---- layer 1: x(64) -> 64, relu ----
    k_gemm<64, 64><<<cdiv(N, 32), B, 0, stream>>>(x, W1, bufH, N);
    k_aggregate<64, true><<<cdiv(N * 64, B), B, 0, stream>>>(
        bufH, dis, row_start, csr, b1, bufX, N);

    // ---- layer 2: 64 -> 64, relu ----
    k_gemm<64, 64><<<cdiv(N, 32), B, 0, stream>>>(bufX, W2, bufH, N);
    k_aggregate<64, true><<<cdiv(N * 64, B), B, 0, stream>>>(
        bufH, dis, row_start, csr, b2, bufX, N);

    // ---- layer 3: 64 -> 32, no relu ----
    k_gemm<64, 32><<<cdiv(N, 64), B, 0, stream>>>(bufX, W3, bufH, N);
    k_aggregate<32, false><<<cdiv(N * 64, B), B, 0, stream>>>(
        bufH, dis, row_start, csr, b3, out, N);
}